// Round 1
// 433.974 us; speedup vs baseline: 1.0037x; 1.0037x over previous
//
#include <hip/hip_runtime.h>

// EdgeFeatGAE: 2-layer GCN (R=4 relations share x, W1, W2), out = sum over
// embed dim -> [R, N].
// Algebra: layer2 collapses to scalar per node (wrow[j] = sum_k W2[j][k]);
// H0 = x@W1 is relation-independent; q[i] = dinv_i * g_i makes layer2 a pure
// scalar gather: out_i = dinv_i*(sum_src q[src] + q[i]) + sum(b2).
// R3: radix-partition into 512-node dst buckets (coalesced writes).
// R5: pack 16 records per wave gather instr (4 lanes x 16B fp16 row chunks),
// exact CSR via per-bucket counting sort, register accumulation. 1738->510us.
// R6/7: k_gemm_h0 vectorized (scalar-load-issue bound). 510->481us.
// R8: dynamic bucket cursors kill hist+scan kernels; in-LDS sort. 481->467us.
// R9: k_scat2 was occupancy-starved (19% occ, 45.5KB LDS -> 3 blocks/CU,
// VALU 4.7%, latency-bound). CH 8192->4096: 24.2KB LDS -> 6 blocks/CU,
// 2x grid -> 4x resident waves.
// R10: k_l1 is VALU-issue bound (VALUBusy 66%, FETCH 223MB @ 2.2TB/s = only
// 27% of peak, occupancy 77%). Hot loop paid 8 cvt + 8 fma per record-quad
// plus a 48-instr fp32 slot reduction. Switch accumulation to packed fp16
// (v_pk_fma_f16, 4 regs) and do the slot reduction packed (24 instrs);
// unpack to fp32 only in the epilogue. k_l2: 16 lanes/node (mean deg ~16;
// halves wave count, 4-round reduction).

constexpr int N    = 100000;
constexpr int E    = 1600000;
constexpr int R    = 4;
constexpr int FEAT = 128;
constexpr int HID  = 32;
constexpr int EMB  = 16;
constexpr int M    = R * N;
constexpr int BS   = 256;
constexpr int SH    = 9;                          // bucket = dst >> 9
constexpr int BSPAN = 1 << SH;                    // 512 nodes per bucket
constexpr int NBUCK = (N + BSPAN - 1) / BSPAN;    // 196 buckets per relation
constexpr int CH    = 4096;                       // edges per partition block (R9)
constexpr int NBKr  = (E + CH - 1) / CH;          // 391 blocks per relation
constexpr int RB    = R * NBUCK;                  // 784 buckets total
constexpr int CAP   = 8960;                       // bucket capacity (mean 8192 + 8.5 sigma)

typedef _Float16 half8 __attribute__((ext_vector_type(8)));   // 16B chunk
typedef _Float16 half2v __attribute__((ext_vector_type(2)));  // packed pair

// ---------------- H0 = x @ W1  [N,32] -> fp16 ----------------
__global__ void k_gemm_h0(const float* __restrict__ x, const float* __restrict__ W1,
                          _Float16* __restrict__ H0h) {
    int t = blockIdx.x * blockDim.x + threadIdx.x;
    if (t >= N * 4) return;
    int i = t >> 2;            // node
    int jh = t & 3;            // j-octet: j = jh*8
    const float4* xr = (const float4*)(x + (size_t)i * FEAT);
    float acc[8];
#pragma unroll
    for (int kk = 0; kk < 8; ++kk) acc[kk] = 0.f;
#pragma unroll 4
    for (int k4 = 0; k4 < FEAT / 4; ++k4) {
        float4 xv = xr[k4];
        float xk[4] = {xv.x, xv.y, xv.z, xv.w};
        const float* wb = W1 + (k4 * 4) * HID + (jh << 3);
#pragma unroll
        for (int dk = 0; dk < 4; ++dk) {
            float4 wlo = *(const float4*)(wb + dk * HID);
            float4 whi = *(const float4*)(wb + dk * HID + 4);
            acc[0] = fmaf(xk[dk], wlo.x, acc[0]);
            acc[1] = fmaf(xk[dk], wlo.y, acc[1]);
            acc[2] = fmaf(xk[dk], wlo.z, acc[2]);
            acc[3] = fmaf(xk[dk], wlo.w, acc[3]);
            acc[4] = fmaf(xk[dk], whi.x, acc[4]);
            acc[5] = fmaf(xk[dk], whi.y, acc[5]);
            acc[6] = fmaf(xk[dk], whi.z, acc[6]);
            acc[7] = fmaf(xk[dk], whi.w, acc[7]);
        }
    }
    half8 hv;
#pragma unroll
    for (int kk = 0; kk < 8; ++kk) hv[kk] = (_Float16)acc[kk];
    ((half8*)H0h)[i * 4 + jh] = hv;    // 16B store, coalesced across lanes
}

// ---------------- wrow[j] = sum_k W2[j][k]; wrowbuf[32] = sum(b2) ----------
__global__ void k_wrow(const float* __restrict__ W2, const float* __restrict__ b2,
                       float* __restrict__ wrowbuf) {
    int j = threadIdx.x;
    if (j < HID) {
        float s = 0.f;
#pragma unroll
        for (int k = 0; k < EMB; ++k) s += W2[j * EMB + k];
        wrowbuf[j] = s;
    } else if (j == HID) {
        float s = 0.f;
#pragma unroll
        for (int k = 0; k < EMB; ++k) s += b2[k];
        wrowbuf[HID] = s;
    }
}

// ---------------- partition: LDS-staged, dynamic bucket-cursor reservation --
__global__ void k_scat2(const int* __restrict__ eis, int* __restrict__ gcur,
                        int* __restrict__ binned) {
    __shared__ int hist[NBUCK], lstart[NBUCK], cursor[NBUCK], gbase[NBUCK];
    __shared__ int sc[BS];
    __shared__ int shuf[CH];              // 16 KB (R9)
    __shared__ unsigned char bkt[CH];     // 4 KB
    int r = blockIdx.x / NBKr, k = blockIdx.x - r * NBKr;
    const int* srcp = eis + (size_t)r * 2 * E;
    const int* dstp = srcp + E;
    int e0 = k * CH, n = min(CH, E - e0);
    for (int b = threadIdx.x; b < NBUCK; b += BS) hist[b] = 0;
    __syncthreads();
    for (int i = threadIdx.x; i < n; i += BS)
        atomicAdd(&hist[dstp[e0 + i] >> SH], 1);
    __syncthreads();
    // exclusive prefix over NBUCK (<= BS) entries
    int v = (threadIdx.x < NBUCK) ? hist[threadIdx.x] : 0;
    sc[threadIdx.x] = v;
    __syncthreads();
#pragma unroll
    for (int d = 1; d < BS; d <<= 1) {
        int x = (threadIdx.x >= d) ? sc[threadIdx.x - d] : 0;
        __syncthreads();
        sc[threadIdx.x] += x;
        __syncthreads();
    }
    if (threadIdx.x < NBUCK) {
        int ex = sc[threadIdx.x] - v;
        lstart[threadIdx.x] = ex;
        cursor[threadIdx.x] = ex;
        // reserve a contiguous range in this bucket's segment
        gbase[threadIdx.x] = atomicAdd(&gcur[r * NBUCK + threadIdx.x], v);
    }
    __syncthreads();
    // local scatter into LDS (bucket-ordered)
    for (int i = threadIdx.x; i < n; i += BS) {
        int d = dstp[e0 + i];
        int b = d >> SH;
        int pos = atomicAdd(&cursor[b], 1);
        shuf[pos] = ((d & (BSPAN - 1)) << 17) | srcp[e0 + i];   // src < 2^17
        bkt[pos]  = (unsigned char)b;
    }
    __syncthreads();
    // coalesced emission into CAP-strided bucket segments
    for (int i = threadIdx.x; i < n; i += BS) {
        int b = bkt[i];
        int pos = gbase[b] + (i - lstart[b]);
        if (pos < CAP)
            binned[(size_t)(r * NBUCK + b) * CAP + pos] = shuf[i];
    }
}

// ---------------- per-bucket in-LDS counting sort (in place) + CSR + dinv ---
__global__ __launch_bounds__(BSPAN)
void k_sort3(const int* __restrict__ gcur, int* __restrict__ binned,
             int* __restrict__ off, int* __restrict__ cnt,
             float* __restrict__ dinv) {
    __shared__ int shuf[CAP];                       // 35.8 KB
    __shared__ int hist[BSPAN], sc[BSPAN], cur[BSPAN];  // 6 KB
    int gb = blockIdx.x;
    int r = gb / NBUCK, b = gb - r * NBUCK;
    int n = min(gcur[gb], CAP);
    int base = gb * CAP;
    int tid = threadIdx.x;            // 0..511
    hist[tid] = 0;
    for (int i = tid; i < n; i += BSPAN) shuf[i] = binned[base + i];  // coalesced
    __syncthreads();
    for (int i = tid; i < n; i += BSPAN)
        atomicAdd(&hist[((unsigned)shuf[i]) >> 17], 1);
    __syncthreads();
    int v = hist[tid];
    sc[tid] = v;
    __syncthreads();
#pragma unroll
    for (int d = 1; d < BSPAN; d <<= 1) {
        int x = (tid >= d) ? sc[tid - d] : 0;
        __syncthreads();
        sc[tid] += x;
        __syncthreads();
    }
    int ex = sc[tid] - v;
    cur[tid] = ex;
    int node = (b << SH) + tid;
    if (node < N) {
        int ri = r * N + node;
        off[ri] = base + ex;
        cnt[ri] = v;
        dinv[ri] = rsqrtf((float)v + 1.0f);
    }
    __syncthreads();
    // scatter src back over binned, sorted by node (reads from LDS only)
    for (int i = tid; i < n; i += BSPAN) {
        int rc = shuf[i];
        int pos = atomicAdd(&cur[((unsigned)rc) >> 17], 1);
        binned[base + pos] = rc & 0x1FFFF;
    }
}

// ---------------- layer 1: 32 lanes/node, 4 lanes/record, packed fp16 acc ---
// One wave64 gather instruction carries 16 random 64B fp16 rows.
// R10: accumulate in 4x half2 via v_pk_fma_f16; packed slot reduction.
__global__ void k_l1(const int* __restrict__ off, const int* __restrict__ cnt,
                     const int* __restrict__ ssrc, const float* __restrict__ dinv,
                     const half8* __restrict__ H0h, const float* __restrict__ b1,
                     const float* __restrict__ wrowbuf, float* __restrict__ q) {
    int t = blockIdx.x * blockDim.x + threadIdx.x;
    int ri = t >> 5;
    if (ri >= M) return;
    int lane = t & 31;
    int c   = lane & 3;        // 16B chunk of the 64B row
    int sub = lane >> 2;       // record slot 0..7
    int i = ri % N;
    int rbase = ri - i;
    float di = dinv[ri];
    half8 hs = H0h[i * 4 + c];                 // self row chunk
    half2v acc2[4];
    half2v zz = {(_Float16)0.f, (_Float16)0.f};
#pragma unroll
    for (int kk = 0; kk < 4; ++kk) acc2[kk] = zz;
    int base = off[ri], n = cnt[ri];
    for (int k0 = 0; k0 < n; k0 += 32) {
        int sb_ = (k0 + lane < n) ? ssrc[base + k0 + lane] : 0;   // coalesced
        int m = n - k0;                         // records left in this window
        for (int bq = 0; bq < 4 && bq * 8 < m; ++bq) {
            int slot = bq * 8 + sub;
            int sj = __shfl(sb_, slot, 32);
            float dv = (slot < m) ? dinv[rbase + sj] : 0.f;
            _Float16 dvh = (_Float16)dv;
            half2v dv2 = {dvh, dvh};
            half8 h = H0h[sj * 4 + c];          // 16B/lane -> 16 rows per wave instr
#pragma unroll
            for (int kk = 0; kk < 4; ++kk) {
                half2v hp = {h[2 * kk], h[2 * kk + 1]};
                acc2[kk] = dv2 * hp + acc2[kk];   // v_pk_fma_f16
            }
        }
    }
    // packed reduction over record slots (lanes c, c+4, ..., c+28 same chunk)
#pragma unroll
    for (int o = 4; o <= 16; o <<= 1) {
#pragma unroll
        for (int kk = 0; kk < 4; ++kk) {
            int av = __builtin_bit_cast(int, acc2[kk]);
            av = __shfl_xor(av, o, 32);
            acc2[kk] = acc2[kk] + __builtin_bit_cast(half2v, av);  // v_pk_add_f16
        }
    }
    // epilogue: h1 = relu(di*acc + di^2*H0self + b1); p = h1 . wrow
    float di2 = di * di;
    float p = 0.f;
#pragma unroll
    for (int kk = 0; kk < 8; ++kk) {
        float av = (float)acc2[kk >> 1][kk & 1];
        int j = c * 8 + kk;
        float h1 = fmaf(di, av, fmaf(di2, (float)hs[kk], b1[j]));
        h1 = fmaxf(h1, 0.f);
        p = fmaf(h1, wrowbuf[j], p);
    }
    p += __shfl_xor(p, 1, 32);
    p += __shfl_xor(p, 2, 32);
    if (lane == 0) q[ri] = di * p;              // q = dinv * g
}

// ---------------- layer 2: per-lane scalar gathers of q + finalize ----------
// R10: 16 lanes/node (mean deg ~16): halves wave count, 4-round reduction.
__global__ void k_l2(const int* __restrict__ off, const int* __restrict__ cnt,
                     const int* __restrict__ ssrc, const float* __restrict__ dinv,
                     const float* __restrict__ q, const float* __restrict__ wrowbuf,
                     float* __restrict__ out) {
    int t = blockIdx.x * blockDim.x + threadIdx.x;
    int ri = t >> 4;
    if (ri >= M) return;
    int lane = t & 15;
    int i = ri % N;
    int rbase = ri - i;
    int base = off[ri], n = cnt[ri];
    float val = 0.f;
    for (int idx = lane; idx < n; idx += 16) {
        int s = ssrc[base + idx];               // coalesced
        val += q[rbase + s];                    // 4B gather, 1.6MB L2-resident
    }
#pragma unroll
    for (int o = 8; o > 0; o >>= 1) val += __shfl_xor(val, o, 16);
    if (lane == 0)
        out[ri] = dinv[ri] * (val + q[ri]) + wrowbuf[HID];
}

extern "C" void kernel_launch(void* const* d_in, const int* in_sizes, int n_in,
                              void* d_out, int out_size, void* d_ws, size_t ws_size,
                              hipStream_t stream) {
    const float* x  = (const float*)d_in[0];
    const int*  eis = (const int*)d_in[1];
    const float* W1 = (const float*)d_in[2];
    const float* b1 = (const float*)d_in[3];
    const float* W2 = (const float*)d_in[4];
    const float* b2 = (const float*)d_in[5];
    float* out = (float*)d_out;

    // ws (4B units): H0h [N*16] | dinv [M] | q [M] | off [M] | cnt [M] |
    //   wrowbuf [64] | gcur [RB] | binned [RB*CAP]   -> ~41 MB
    _Float16* H0h = (_Float16*)d_ws;
    float* dinv   = (float*)d_ws + (size_t)N * HID / 2;
    float* q      = dinv + M;
    int*   off    = (int*)(q + M);
    int*   cnt    = off + M;
    float* wrowbuf = (float*)(cnt + M);
    int*   gcur   = (int*)(wrowbuf + 64);
    int*   binned = gcur + RB;

    k_gemm_h0<<<(N * 4 + BS - 1) / BS, BS, 0, stream>>>(x, W1, H0h);
    k_wrow  <<<1, 64, 0, stream>>>(W2, b2, wrowbuf);
    hipMemsetAsync(gcur, 0, (size_t)RB * sizeof(int), stream);
    k_scat2 <<<R * NBKr, BS, 0, stream>>>(eis, gcur, binned);
    k_sort3 <<<RB, BSPAN, 0, stream>>>(gcur, binned, off, cnt, dinv);
    k_l1    <<<(M * 32 + BS - 1) / BS, BS, 0, stream>>>(off, cnt, binned, dinv,
                                                        (const half8*)H0h, b1, wrowbuf, q);
    k_l2    <<<(M * 16 + BS - 1) / BS, BS, 0, stream>>>(off, cnt, binned, dinv, q,
                                                        wrowbuf, out);
}

// Round 2
// 399.230 us; speedup vs baseline: 1.0911x; 1.0870x over previous
//
#include <hip/hip_runtime.h>

// EdgeFeatGAE: 2-layer GCN (R=4 relations share x, W1, W2), out = sum over
// embed dim -> [R, N].
// Algebra: layer2 collapses to scalar per node (wrow[j] = sum_k W2[j][k]);
// H0 = x@W1 is relation-independent; q[i] = dinv_i * g_i makes layer2 a pure
// scalar gather: out_i = dinv_i*(sum_src q[src] + q[i]) + sum(b2).
// R3: radix-partition into 512-node dst buckets (coalesced writes).
// R5: pack 16 records per wave gather instr (4 lanes x 16B fp16 row chunks),
// exact CSR via per-bucket counting sort, register accumulation. 1738->510us.
// R6/7: k_gemm_h0 vectorized (scalar-load-issue bound). 510->481us.
// R8: dynamic bucket cursors kill hist+scan kernels; in-LDS sort. 481->467us.
// R9: k_scat2 occupancy: CH 8192->4096 -> 6 blocks/CU. 467->436us.
// R10: packed-fp16 acc in k_l1 FAILED (VALUBusy 66->47% but dur 104->114us):
// k_l1 is LATENCY-bound on the gather chain, not VALU-issue bound. fp16 cvt
// on the dv path + 4 acc chains hurt ILP. k_l2 16-lane change was good.
// R11: k_l1 back to fp32 acc, 16 lanes/node: 4 independent node-chains per
// wave (2x MLP), half the waves, half the per-node prologue/epilogue issue,
// 2-round slot reduction. Mean degree = 16 -> 16-record window fits typical
// node in one pass. k_l2 -> 8 lanes/node for the same reason.

constexpr int N    = 100000;
constexpr int E    = 1600000;
constexpr int R    = 4;
constexpr int FEAT = 128;
constexpr int HID  = 32;
constexpr int EMB  = 16;
constexpr int M    = R * N;
constexpr int BS   = 256;
constexpr int SH    = 9;                          // bucket = dst >> 9
constexpr int BSPAN = 1 << SH;                    // 512 nodes per bucket
constexpr int NBUCK = (N + BSPAN - 1) / BSPAN;    // 196 buckets per relation
constexpr int CH    = 4096;                       // edges per partition block (R9)
constexpr int NBKr  = (E + CH - 1) / CH;          // 391 blocks per relation
constexpr int RB    = R * NBUCK;                  // 784 buckets total
constexpr int CAP   = 8960;                       // bucket capacity (mean 8192 + 8.5 sigma)

typedef _Float16 half8 __attribute__((ext_vector_type(8)));   // 16B chunk

// ---------------- H0 = x @ W1  [N,32] -> fp16 ----------------
__global__ void k_gemm_h0(const float* __restrict__ x, const float* __restrict__ W1,
                          _Float16* __restrict__ H0h) {
    int t = blockIdx.x * blockDim.x + threadIdx.x;
    if (t >= N * 4) return;
    int i = t >> 2;            // node
    int jh = t & 3;            // j-octet: j = jh*8
    const float4* xr = (const float4*)(x + (size_t)i * FEAT);
    float acc[8];
#pragma unroll
    for (int kk = 0; kk < 8; ++kk) acc[kk] = 0.f;
#pragma unroll 4
    for (int k4 = 0; k4 < FEAT / 4; ++k4) {
        float4 xv = xr[k4];
        float xk[4] = {xv.x, xv.y, xv.z, xv.w};
        const float* wb = W1 + (k4 * 4) * HID + (jh << 3);
#pragma unroll
        for (int dk = 0; dk < 4; ++dk) {
            float4 wlo = *(const float4*)(wb + dk * HID);
            float4 whi = *(const float4*)(wb + dk * HID + 4);
            acc[0] = fmaf(xk[dk], wlo.x, acc[0]);
            acc[1] = fmaf(xk[dk], wlo.y, acc[1]);
            acc[2] = fmaf(xk[dk], wlo.z, acc[2]);
            acc[3] = fmaf(xk[dk], wlo.w, acc[3]);
            acc[4] = fmaf(xk[dk], whi.x, acc[4]);
            acc[5] = fmaf(xk[dk], whi.y, acc[5]);
            acc[6] = fmaf(xk[dk], whi.z, acc[6]);
            acc[7] = fmaf(xk[dk], whi.w, acc[7]);
        }
    }
    half8 hv;
#pragma unroll
    for (int kk = 0; kk < 8; ++kk) hv[kk] = (_Float16)acc[kk];
    ((half8*)H0h)[i * 4 + jh] = hv;    // 16B store, coalesced across lanes
}

// ---------------- wrow[j] = sum_k W2[j][k]; wrowbuf[32] = sum(b2) ----------
__global__ void k_wrow(const float* __restrict__ W2, const float* __restrict__ b2,
                       float* __restrict__ wrowbuf) {
    int j = threadIdx.x;
    if (j < HID) {
        float s = 0.f;
#pragma unroll
        for (int k = 0; k < EMB; ++k) s += W2[j * EMB + k];
        wrowbuf[j] = s;
    } else if (j == HID) {
        float s = 0.f;
#pragma unroll
        for (int k = 0; k < EMB; ++k) s += b2[k];
        wrowbuf[HID] = s;
    }
}

// ---------------- partition: LDS-staged, dynamic bucket-cursor reservation --
__global__ void k_scat2(const int* __restrict__ eis, int* __restrict__ gcur,
                        int* __restrict__ binned) {
    __shared__ int hist[NBUCK], lstart[NBUCK], cursor[NBUCK], gbase[NBUCK];
    __shared__ int sc[BS];
    __shared__ int shuf[CH];              // 16 KB (R9)
    __shared__ unsigned char bkt[CH];     // 4 KB
    int r = blockIdx.x / NBKr, k = blockIdx.x - r * NBKr;
    const int* srcp = eis + (size_t)r * 2 * E;
    const int* dstp = srcp + E;
    int e0 = k * CH, n = min(CH, E - e0);
    for (int b = threadIdx.x; b < NBUCK; b += BS) hist[b] = 0;
    __syncthreads();
    for (int i = threadIdx.x; i < n; i += BS)
        atomicAdd(&hist[dstp[e0 + i] >> SH], 1);
    __syncthreads();
    // exclusive prefix over NBUCK (<= BS) entries
    int v = (threadIdx.x < NBUCK) ? hist[threadIdx.x] : 0;
    sc[threadIdx.x] = v;
    __syncthreads();
#pragma unroll
    for (int d = 1; d < BS; d <<= 1) {
        int x = (threadIdx.x >= d) ? sc[threadIdx.x - d] : 0;
        __syncthreads();
        sc[threadIdx.x] += x;
        __syncthreads();
    }
    if (threadIdx.x < NBUCK) {
        int ex = sc[threadIdx.x] - v;
        lstart[threadIdx.x] = ex;
        cursor[threadIdx.x] = ex;
        // reserve a contiguous range in this bucket's segment
        gbase[threadIdx.x] = atomicAdd(&gcur[r * NBUCK + threadIdx.x], v);
    }
    __syncthreads();
    // local scatter into LDS (bucket-ordered)
    for (int i = threadIdx.x; i < n; i += BS) {
        int d = dstp[e0 + i];
        int b = d >> SH;
        int pos = atomicAdd(&cursor[b], 1);
        shuf[pos] = ((d & (BSPAN - 1)) << 17) | srcp[e0 + i];   // src < 2^17
        bkt[pos]  = (unsigned char)b;
    }
    __syncthreads();
    // coalesced emission into CAP-strided bucket segments
    for (int i = threadIdx.x; i < n; i += BS) {
        int b = bkt[i];
        int pos = gbase[b] + (i - lstart[b]);
        if (pos < CAP)
            binned[(size_t)(r * NBUCK + b) * CAP + pos] = shuf[i];
    }
}

// ---------------- per-bucket in-LDS counting sort (in place) + CSR + dinv ---
__global__ __launch_bounds__(BSPAN)
void k_sort3(const int* __restrict__ gcur, int* __restrict__ binned,
             int* __restrict__ off, int* __restrict__ cnt,
             float* __restrict__ dinv) {
    __shared__ int shuf[CAP];                       // 35.8 KB
    __shared__ int hist[BSPAN], sc[BSPAN], cur[BSPAN];  // 6 KB
    int gb = blockIdx.x;
    int r = gb / NBUCK, b = gb - r * NBUCK;
    int n = min(gcur[gb], CAP);
    int base = gb * CAP;
    int tid = threadIdx.x;            // 0..511
    hist[tid] = 0;
    for (int i = tid; i < n; i += BSPAN) shuf[i] = binned[base + i];  // coalesced
    __syncthreads();
    for (int i = tid; i < n; i += BSPAN)
        atomicAdd(&hist[((unsigned)shuf[i]) >> 17], 1);
    __syncthreads();
    int v = hist[tid];
    sc[tid] = v;
    __syncthreads();
#pragma unroll
    for (int d = 1; d < BSPAN; d <<= 1) {
        int x = (tid >= d) ? sc[tid - d] : 0;
        __syncthreads();
        sc[tid] += x;
        __syncthreads();
    }
    int ex = sc[tid] - v;
    cur[tid] = ex;
    int node = (b << SH) + tid;
    if (node < N) {
        int ri = r * N + node;
        off[ri] = base + ex;
        cnt[ri] = v;
        dinv[ri] = rsqrtf((float)v + 1.0f);
    }
    __syncthreads();
    // scatter src back over binned, sorted by node (reads from LDS only)
    for (int i = tid; i < n; i += BSPAN) {
        int rc = shuf[i];
        int pos = atomicAdd(&cur[((unsigned)rc) >> 17], 1);
        binned[base + pos] = rc & 0x1FFFF;
    }
}

// ---------------- layer 1: 16 lanes/node, 4 lanes/record, fp32 acc ---------
// One wave64 gather instruction still carries 16 random 64B fp16 rows, but a
// wave now holds 4 independent node gather-chains (R11: 2x MLP vs 32L).
__global__ void k_l1(const int* __restrict__ off, const int* __restrict__ cnt,
                     const int* __restrict__ ssrc, const float* __restrict__ dinv,
                     const half8* __restrict__ H0h, const float* __restrict__ b1,
                     const float* __restrict__ wrowbuf, float* __restrict__ q) {
    int t = blockIdx.x * blockDim.x + threadIdx.x;
    int ri = t >> 4;
    if (ri >= M) return;
    int lane = t & 15;
    int c   = lane & 3;        // 16B chunk of the 64B row
    int sub = lane >> 2;       // record slot 0..3
    int i = ri % N;
    int rbase = ri - i;
    float di = dinv[ri];
    half8 hs = H0h[i * 4 + c];                 // self row chunk
    float acc[8];
#pragma unroll
    for (int kk = 0; kk < 8; ++kk) acc[kk] = 0.f;
    int base = off[ri], n = cnt[ri];
    for (int k0 = 0; k0 < n; k0 += 16) {
        int sb_ = (k0 + lane < n) ? ssrc[base + k0 + lane] : 0;   // coalesced
        int m = n - k0;                         // records left in this window
        for (int bq = 0; bq < 4 && bq * 4 < m; ++bq) {
            int slot = bq * 4 + sub;
            int sj = __shfl(sb_, slot, 16);
            float dv = (slot < m) ? dinv[rbase + sj] : 0.f;
            half8 h = H0h[sj * 4 + c];          // 16B/lane -> 16 rows per wave instr
#pragma unroll
            for (int kk = 0; kk < 8; ++kk)
                acc[kk] = fmaf(dv, (float)h[kk], acc[kk]);
        }
    }
    // reduce over record slots (lanes c, c+4, c+8, c+12 hold same chunk)
#pragma unroll
    for (int o = 4; o <= 8; o <<= 1)
#pragma unroll
        for (int kk = 0; kk < 8; ++kk) acc[kk] += __shfl_xor(acc[kk], o, 16);
    // epilogue: h1 = relu(di*acc + di^2*H0self + b1); p = h1 . wrow
    float di2 = di * di;
    float p = 0.f;
#pragma unroll
    for (int kk = 0; kk < 8; ++kk) {
        int j = c * 8 + kk;
        float h1 = fmaf(di, acc[kk], fmaf(di2, (float)hs[kk], b1[j]));
        h1 = fmaxf(h1, 0.f);
        p = fmaf(h1, wrowbuf[j], p);
    }
    p += __shfl_xor(p, 1, 16);
    p += __shfl_xor(p, 2, 16);
    if (lane == 0) q[ri] = di * p;              // q = dinv * g
}

// ---------------- layer 2: per-lane scalar gathers of q + finalize ----------
// R11: 8 lanes/node (mean deg 16 -> 2 gather rounds; 8 node-chains per wave).
__global__ void k_l2(const int* __restrict__ off, const int* __restrict__ cnt,
                     const int* __restrict__ ssrc, const float* __restrict__ dinv,
                     const float* __restrict__ q, const float* __restrict__ wrowbuf,
                     float* __restrict__ out) {
    int t = blockIdx.x * blockDim.x + threadIdx.x;
    int ri = t >> 3;
    if (ri >= M) return;
    int lane = t & 7;
    int i = ri % N;
    int rbase = ri - i;
    int base = off[ri], n = cnt[ri];
    float val = 0.f;
    for (int idx = lane; idx < n; idx += 8) {
        int s = ssrc[base + idx];               // coalesced
        val += q[rbase + s];                    // 4B gather, 1.6MB L2-resident
    }
#pragma unroll
    for (int o = 4; o > 0; o >>= 1) val += __shfl_xor(val, o, 8);
    if (lane == 0)
        out[ri] = dinv[ri] * (val + q[ri]) + wrowbuf[HID];
}

extern "C" void kernel_launch(void* const* d_in, const int* in_sizes, int n_in,
                              void* d_out, int out_size, void* d_ws, size_t ws_size,
                              hipStream_t stream) {
    const float* x  = (const float*)d_in[0];
    const int*  eis = (const int*)d_in[1];
    const float* W1 = (const float*)d_in[2];
    const float* b1 = (const float*)d_in[3];
    const float* W2 = (const float*)d_in[4];
    const float* b2 = (const float*)d_in[5];
    float* out = (float*)d_out;

    // ws (4B units): H0h [N*16] | dinv [M] | q [M] | off [M] | cnt [M] |
    //   wrowbuf [64] | gcur [RB] | binned [RB*CAP]   -> ~41 MB
    _Float16* H0h = (_Float16*)d_ws;
    float* dinv   = (float*)d_ws + (size_t)N * HID / 2;
    float* q      = dinv + M;
    int*   off    = (int*)(q + M);
    int*   cnt    = off + M;
    float* wrowbuf = (float*)(cnt + M);
    int*   gcur   = (int*)(wrowbuf + 64);
    int*   binned = gcur + RB;

    k_gemm_h0<<<(N * 4 + BS - 1) / BS, BS, 0, stream>>>(x, W1, H0h);
    k_wrow  <<<1, 64, 0, stream>>>(W2, b2, wrowbuf);
    hipMemsetAsync(gcur, 0, (size_t)RB * sizeof(int), stream);
    k_scat2 <<<R * NBKr, BS, 0, stream>>>(eis, gcur, binned);
    k_sort3 <<<RB, BSPAN, 0, stream>>>(gcur, binned, off, cnt, dinv);
    k_l1    <<<(M * 16 + BS - 1) / BS, BS, 0, stream>>>(off, cnt, binned, dinv,
                                                        (const half8*)H0h, b1, wrowbuf, q);
    k_l2    <<<(M * 8 + BS - 1) / BS, BS, 0, stream>>>(off, cnt, binned, dinv, q,
                                                       wrowbuf, out);
}

// Round 3
// 391.786 us; speedup vs baseline: 1.1118x; 1.0190x over previous
//
#include <hip/hip_runtime.h>

// EdgeFeatGAE: 2-layer GCN (R=4 relations share x, W1, W2), out = sum over
// embed dim -> [R, N].
// Algebra: layer2 collapses to scalar per node (wrow[j] = sum_k W2[j][k]);
// H0 = x@W1 is relation-independent; q[i] = dinv_i * g_i makes layer2 a pure
// scalar gather: out_i = dinv_i*(sum_src q[src] + q[i]) + sum(b2).
// R3: radix-partition into 512-node dst buckets (coalesced writes).
// R5: pack 16 records per wave gather instr (4 lanes x 16B fp16 row chunks),
// exact CSR via per-bucket counting sort, register accumulation. 1738->510us.
// R6/7: k_gemm_h0 vectorized (scalar-load-issue bound). 510->481us.
// R8: dynamic bucket cursors kill hist+scan kernels; in-LDS sort. 481->467us.
// R9: k_scat2 occupancy: CH 8192->4096 -> 6 blocks/CU. 467->436us.
// R10: packed-fp16 acc in k_l1 FAILED (VALUBusy 66->47% but dur 104->114us):
// k_l1 is LATENCY-bound on the gather chain. fp16 cvt on the dv path + 4 acc
// chains hurt ILP. k_l2 16-lane change was good.
// R11: k_l1 fp32 acc, 16 lanes/node -> 4 node-chains/wave. 436->399us
// (k_l1 104->86.5us, matched prediction).
// R12: half of k_l1's gather VMEM was dinv[src] (4 lanes loading the SAME
// address per record). Pre-scale: Hsc[ri] = dinv[ri]*H0[i] (fp16, +zero row)
// -> layer1 is a pure add-gather: h1 = di*(sum Hsc[src] + Hsc[self]) + b1.
// Accumulate packed fp16 (4x v_pk_add_f16/record; R10 proved fp16 acc is
// numerically safe - absmax pinned at the 2^-8 H0h storage floor; R10's
// regression was the cvt-on-dv dep chain, now gone). Per-quad: ~22 VALU +
// 2 VMEM -> ~6 VALU + 1 VMEM. Also: shfl_up wave scans replace 18-barrier
// LDS scans in k_scat2/k_sort3 (sort3 LDS 41.8->40.0KB -> 4 blocks/CU).

constexpr int N    = 100000;
constexpr int E    = 1600000;
constexpr int R    = 4;
constexpr int FEAT = 128;
constexpr int HID  = 32;
constexpr int EMB  = 16;
constexpr int M    = R * N;
constexpr int BS   = 256;
constexpr int SH    = 9;                          // bucket = dst >> 9
constexpr int BSPAN = 1 << SH;                    // 512 nodes per bucket
constexpr int NBUCK = (N + BSPAN - 1) / BSPAN;    // 196 buckets per relation
constexpr int CH    = 4096;                       // edges per partition block (R9)
constexpr int NBKr  = (E + CH - 1) / CH;          // 391 blocks per relation
constexpr int RB    = R * NBUCK;                  // 784 buckets total
constexpr int CAP   = 8960;                       // bucket capacity (mean 8192 + 8.5 sigma)

typedef _Float16 half8 __attribute__((ext_vector_type(8)));   // 16B chunk
typedef _Float16 half2v __attribute__((ext_vector_type(2)));  // packed pair

// ---------------- H0 = x @ W1  [N,32] -> fp16 ----------------
__global__ void k_gemm_h0(const float* __restrict__ x, const float* __restrict__ W1,
                          _Float16* __restrict__ H0h) {
    int t = blockIdx.x * blockDim.x + threadIdx.x;
    if (t >= N * 4) return;
    int i = t >> 2;            // node
    int jh = t & 3;            // j-octet: j = jh*8
    const float4* xr = (const float4*)(x + (size_t)i * FEAT);
    float acc[8];
#pragma unroll
    for (int kk = 0; kk < 8; ++kk) acc[kk] = 0.f;
#pragma unroll 4
    for (int k4 = 0; k4 < FEAT / 4; ++k4) {
        float4 xv = xr[k4];
        float xk[4] = {xv.x, xv.y, xv.z, xv.w};
        const float* wb = W1 + (k4 * 4) * HID + (jh << 3);
#pragma unroll
        for (int dk = 0; dk < 4; ++dk) {
            float4 wlo = *(const float4*)(wb + dk * HID);
            float4 whi = *(const float4*)(wb + dk * HID + 4);
            acc[0] = fmaf(xk[dk], wlo.x, acc[0]);
            acc[1] = fmaf(xk[dk], wlo.y, acc[1]);
            acc[2] = fmaf(xk[dk], wlo.z, acc[2]);
            acc[3] = fmaf(xk[dk], wlo.w, acc[3]);
            acc[4] = fmaf(xk[dk], whi.x, acc[4]);
            acc[5] = fmaf(xk[dk], whi.y, acc[5]);
            acc[6] = fmaf(xk[dk], whi.z, acc[6]);
            acc[7] = fmaf(xk[dk], whi.w, acc[7]);
        }
    }
    half8 hv;
#pragma unroll
    for (int kk = 0; kk < 8; ++kk) hv[kk] = (_Float16)acc[kk];
    ((half8*)H0h)[i * 4 + jh] = hv;    // 16B store, coalesced across lanes
}

// ---------------- wrow[j] = sum_k W2[j][k]; wrowbuf[32] = sum(b2) ----------
__global__ void k_wrow(const float* __restrict__ W2, const float* __restrict__ b2,
                       float* __restrict__ wrowbuf) {
    int j = threadIdx.x;
    if (j < HID) {
        float s = 0.f;
#pragma unroll
        for (int k = 0; k < EMB; ++k) s += W2[j * EMB + k];
        wrowbuf[j] = s;
    } else if (j == HID) {
        float s = 0.f;
#pragma unroll
        for (int k = 0; k < EMB; ++k) s += b2[k];
        wrowbuf[HID] = s;
    }
}

// ---------------- partition: LDS-staged, dynamic bucket-cursor reservation --
__global__ void k_scat2(const int* __restrict__ eis, int* __restrict__ gcur,
                        int* __restrict__ binned) {
    __shared__ int hist[NBUCK], lstart[NBUCK], cursor[NBUCK], gbase[NBUCK];
    __shared__ int wpart[BS / 64];
    __shared__ int shuf[CH];              // 16 KB (R9)
    __shared__ unsigned char bkt[CH];     // 4 KB
    int r = blockIdx.x / NBKr, k = blockIdx.x - r * NBKr;
    const int* srcp = eis + (size_t)r * 2 * E;
    const int* dstp = srcp + E;
    int e0 = k * CH, n = min(CH, E - e0);
    for (int b = threadIdx.x; b < NBUCK; b += BS) hist[b] = 0;
    __syncthreads();
    for (int i = threadIdx.x; i < n; i += BS)
        atomicAdd(&hist[dstp[e0 + i] >> SH], 1);
    __syncthreads();
    // exclusive prefix over NBUCK (<= BS) entries: wave shfl scan (R12)
    int v = (threadIdx.x < NBUCK) ? hist[threadIdx.x] : 0;
    int lanei = threadIdx.x & 63;
    int s = v;
#pragma unroll
    for (int d = 1; d < 64; d <<= 1) {
        int xup = __shfl_up(s, d, 64);
        s += (lanei >= d) ? xup : 0;
    }
    if (lanei == 63) wpart[threadIdx.x >> 6] = s;
    __syncthreads();
    int offw = 0;
#pragma unroll
    for (int ww = 0; ww < BS / 64; ++ww)
        offw += (ww < (threadIdx.x >> 6)) ? wpart[ww] : 0;
    int ex = offw + s - v;                // exclusive prefix
    if (threadIdx.x < NBUCK) {
        lstart[threadIdx.x] = ex;
        cursor[threadIdx.x] = ex;
        // reserve a contiguous range in this bucket's segment
        gbase[threadIdx.x] = atomicAdd(&gcur[r * NBUCK + threadIdx.x], v);
    }
    __syncthreads();
    // local scatter into LDS (bucket-ordered)
    for (int i = threadIdx.x; i < n; i += BS) {
        int d = dstp[e0 + i];
        int b = d >> SH;
        int pos = atomicAdd(&cursor[b], 1);
        shuf[pos] = ((d & (BSPAN - 1)) << 17) | srcp[e0 + i];   // src < 2^17
        bkt[pos]  = (unsigned char)b;
    }
    __syncthreads();
    // coalesced emission into CAP-strided bucket segments
    for (int i = threadIdx.x; i < n; i += BS) {
        int b = bkt[i];
        int pos = gbase[b] + (i - lstart[b]);
        if (pos < CAP)
            binned[(size_t)(r * NBUCK + b) * CAP + pos] = shuf[i];
    }
}

// ---------------- per-bucket in-LDS counting sort (in place) + CSR + dinv ---
__global__ __launch_bounds__(BSPAN)
void k_sort3(const int* __restrict__ gcur, int* __restrict__ binned,
             int* __restrict__ off, int* __restrict__ cnt,
             float* __restrict__ dinv) {
    __shared__ int shuf[CAP];                       // 35.8 KB
    __shared__ int hist[BSPAN], cur[BSPAN];         // 4 KB
    __shared__ int wpart[BSPAN / 64];
    int gb = blockIdx.x;
    int r = gb / NBUCK, b = gb - r * NBUCK;
    int n = min(gcur[gb], CAP);
    int base = gb * CAP;
    int tid = threadIdx.x;            // 0..511
    hist[tid] = 0;
    for (int i = tid; i < n; i += BSPAN) shuf[i] = binned[base + i];  // coalesced
    __syncthreads();
    for (int i = tid; i < n; i += BSPAN)
        atomicAdd(&hist[((unsigned)shuf[i]) >> 17], 1);
    __syncthreads();
    int v = hist[tid];
    // wave shfl scan + cross-wave pass (R12: 2 barriers vs 18)
    int lanei = tid & 63;
    int s = v;
#pragma unroll
    for (int d = 1; d < 64; d <<= 1) {
        int xup = __shfl_up(s, d, 64);
        s += (lanei >= d) ? xup : 0;
    }
    if (lanei == 63) wpart[tid >> 6] = s;
    __syncthreads();
    int offw = 0;
#pragma unroll
    for (int ww = 0; ww < BSPAN / 64; ++ww)
        offw += (ww < (tid >> 6)) ? wpart[ww] : 0;
    int ex = offw + s - v;                // exclusive prefix
    cur[tid] = ex;
    int node = (b << SH) + tid;
    if (node < N) {
        int ri = r * N + node;
        off[ri] = base + ex;
        cnt[ri] = v;
        dinv[ri] = rsqrtf((float)v + 1.0f);
    }
    __syncthreads();
    // scatter src back over binned, sorted by node (reads from LDS only)
    for (int i = tid; i < n; i += BSPAN) {
        int rc = shuf[i];
        int pos = atomicAdd(&cur[((unsigned)rc) >> 17], 1);
        binned[base + pos] = rc & 0x1FFFF;
    }
}

// ---------------- Hsc[ri] = dinv[ri] * H0[i]  (fp16, + zero row at M) ------
__global__ void k_scale(const float* __restrict__ dinv, const half8* __restrict__ H0h,
                        half8* __restrict__ Hsc) {
    int t = blockIdx.x * blockDim.x + threadIdx.x;
    if (t >= (M + 1) * 4) return;
    int ri = t >> 2, c = t & 3;
    half8 o;
    if (ri == M) {
#pragma unroll
        for (int kk = 0; kk < 8; ++kk) o[kk] = (_Float16)0.f;
    } else {
        int i = ri % N;
        float di = dinv[ri];
        half8 h = H0h[i * 4 + c];
#pragma unroll
        for (int kk = 0; kk < 8; ++kk) o[kk] = (_Float16)(di * (float)h[kk]);
    }
    Hsc[t] = o;
}

// ---------------- layer 1: 16 lanes/node, 4 lanes/record, pure add-gather --
// R12: rows are pre-scaled by dinv[src] -> no dinv gather, no multiply.
// Accumulate packed fp16: 4x v_pk_add_f16 per record. Invalid slots read the
// zero row at index M (1 cndmask on the index).
__global__ void k_l1(const int* __restrict__ off, const int* __restrict__ cnt,
                     const int* __restrict__ ssrc, const float* __restrict__ dinv,
                     const half8* __restrict__ Hsc, const float* __restrict__ b1,
                     const float* __restrict__ wrowbuf, float* __restrict__ q) {
    int t = blockIdx.x * blockDim.x + threadIdx.x;
    int ri = t >> 4;
    if (ri >= M) return;
    int lane = t & 15;
    int c   = lane & 3;        // 16B chunk of the 64B row
    int sub = lane >> 2;       // record slot 0..3
    int i = ri % N;
    int rbase = ri - i;
    float di = dinv[ri];
    half2v acc[4];
    half2v zz = {(_Float16)0.f, (_Float16)0.f};
#pragma unroll
    for (int kk = 0; kk < 4; ++kk) acc[kk] = zz;
    int base = off[ri], n = cnt[ri];
    for (int k0 = 0; k0 < n; k0 += 16) {
        int sb_ = (k0 + lane < n) ? ssrc[base + k0 + lane] : 0;   // coalesced
        int m = n - k0;                         // records left in this window
        for (int bq = 0; bq < 4 && bq * 4 < m; ++bq) {
            int slot = bq * 4 + sub;
            int sj = __shfl(sb_, slot, 16);
            int idx = (slot < m) ? (rbase + sj) : M;   // zero row for pad slots
            half8 h = Hsc[idx * 4 + c];         // 16B/lane -> 16 rows per wave instr
#pragma unroll
            for (int kk = 0; kk < 4; ++kk) {
                half2v hp = {h[2 * kk], h[2 * kk + 1]};
                acc[kk] = acc[kk] + hp;         // v_pk_add_f16
            }
        }
    }
    // packed reduction over record slots (lanes c, c+4, c+8, c+12 same chunk)
#pragma unroll
    for (int o = 4; o <= 8; o <<= 1) {
#pragma unroll
        for (int kk = 0; kk < 4; ++kk) {
            int av = __builtin_bit_cast(int, acc[kk]);
            av = __shfl_xor(av, o, 16);
            acc[kk] = acc[kk] + __builtin_bit_cast(half2v, av);  // v_pk_add_f16
        }
    }
    // self term: + Hsc[ri]  (h1 = di*(sum_src + self) + b1)
    half8 hs = Hsc[ri * 4 + c];
#pragma unroll
    for (int kk = 0; kk < 4; ++kk) {
        half2v hp = {hs[2 * kk], hs[2 * kk + 1]};
        acc[kk] = acc[kk] + hp;
    }
    // epilogue: h1 = relu(di*acc + b1); p = h1 . wrow
    float p = 0.f;
#pragma unroll
    for (int kk = 0; kk < 8; ++kk) {
        float av = (float)acc[kk >> 1][kk & 1];
        int j = c * 8 + kk;
        float h1 = fmaf(di, av, b1[j]);
        h1 = fmaxf(h1, 0.f);
        p = fmaf(h1, wrowbuf[j], p);
    }
    p += __shfl_xor(p, 1, 16);
    p += __shfl_xor(p, 2, 16);
    if (lane == 0) q[ri] = di * p;              // q = dinv * g
}

// ---------------- layer 2: per-lane scalar gathers of q + finalize ----------
// R11: 8 lanes/node (mean deg 16 -> 2 gather rounds; 8 node-chains per wave).
__global__ void k_l2(const int* __restrict__ off, const int* __restrict__ cnt,
                     const int* __restrict__ ssrc, const float* __restrict__ dinv,
                     const float* __restrict__ q, const float* __restrict__ wrowbuf,
                     float* __restrict__ out) {
    int t = blockIdx.x * blockDim.x + threadIdx.x;
    int ri = t >> 3;
    if (ri >= M) return;
    int lane = t & 7;
    int i = ri % N;
    int rbase = ri - i;
    int base = off[ri], n = cnt[ri];
    float val = 0.f;
    for (int idx = lane; idx < n; idx += 8) {
        int s = ssrc[base + idx];               // coalesced
        val += q[rbase + s];                    // 4B gather, 1.6MB L2-resident
    }
#pragma unroll
    for (int o = 4; o > 0; o >>= 1) val += __shfl_xor(val, o, 8);
    if (lane == 0)
        out[ri] = dinv[ri] * (val + q[ri]) + wrowbuf[HID];
}

extern "C" void kernel_launch(void* const* d_in, const int* in_sizes, int n_in,
                              void* d_out, int out_size, void* d_ws, size_t ws_size,
                              hipStream_t stream) {
    const float* x  = (const float*)d_in[0];
    const int*  eis = (const int*)d_in[1];
    const float* W1 = (const float*)d_in[2];
    const float* b1 = (const float*)d_in[3];
    const float* W2 = (const float*)d_in[4];
    const float* b2 = (const float*)d_in[5];
    float* out = (float*)d_out;

    // ws (4B units): H0h [N*16] | dinv [M] | q [M] | off [M] | cnt [M] |
    //   wrowbuf [64] | gcur [RB] | binned [RB*CAP] | Hsc [(M+1)*16]  -> ~67 MB
    _Float16* H0h = (_Float16*)d_ws;
    float* dinv   = (float*)d_ws + (size_t)N * HID / 2;
    float* q      = dinv + M;
    int*   off    = (int*)(q + M);
    int*   cnt    = off + M;
    float* wrowbuf = (float*)(cnt + M);
    int*   gcur   = (int*)(wrowbuf + 64);
    int*   binned = gcur + RB;
    _Float16* Hsc = (_Float16*)(binned + (size_t)RB * CAP);

    k_gemm_h0<<<(N * 4 + BS - 1) / BS, BS, 0, stream>>>(x, W1, H0h);
    k_wrow  <<<1, 64, 0, stream>>>(W2, b2, wrowbuf);
    hipMemsetAsync(gcur, 0, (size_t)RB * sizeof(int), stream);
    k_scat2 <<<R * NBKr, BS, 0, stream>>>(eis, gcur, binned);
    k_sort3 <<<RB, BSPAN, 0, stream>>>(gcur, binned, off, cnt, dinv);
    k_scale <<<((M + 1) * 4 + BS - 1) / BS, BS, 0, stream>>>(dinv, (const half8*)H0h,
                                                             (half8*)Hsc);
    k_l1    <<<(M * 16 + BS - 1) / BS, BS, 0, stream>>>(off, cnt, binned, dinv,
                                                        (const half8*)Hsc, b1, wrowbuf, q);
    k_l2    <<<(M * 8 + BS - 1) / BS, BS, 0, stream>>>(off, cnt, binned, dinv, q,
                                                       wrowbuf, out);
}